// Round 1
// 171.352 us; speedup vs baseline: 1.6943x; 1.6943x over previous
//
#include <hip/hip_runtime.h>
#include <math.h>

// Problem constants (from reference setup_inputs)
constexpr int   BSZ   = 16;
constexpr int   NDIM  = 128;
constexpr int   KP1   = 65537;      // K+1
constexpr long  NDATA = 500000;
constexpr float T_INV = 1.0f / 0.07f;
constexpr float MOM   = 0.5f;
constexpr float EPS   = 1e-12f;

constexpr int U   = 8;    // rows in flight per wave iteration (MLP depth)
constexpr int NBX = 128;  // blocks along k per batch row -> 2048 blocks total

// Persistent-chunk logits kernel.
// Grid: (NBX, BSZ). blockIdx.y = b, so x[b] lives in 2 VGPRs for the whole
// kernel. Each wave owns a contiguous chunk of ~KP1/(NBX*4)=129 rows and
// processes U=8 rows per iteration: 8 independent 512B gathers in flight,
// 8 independent butterfly reductions (shuffle latency hidden by ILP),
// one coalesced 8-lane store. 64 VGPR cap -> 8 waves/SIMD.
__global__ __launch_bounds__(256, 8) void logits_kernel(
        const float*  __restrict__ x,
        const int*    __restrict__ y,
        const int*    __restrict__ idx,
        const float*  __restrict__ memory,
        float*        __restrict__ logits) {
    const int b    = blockIdx.y;
    const int lane = threadIdx.x & 63;
    const int wid  = threadIdx.x >> 6;          // 0..3
    const int nwaves = NBX * 4;
    const int gwave  = blockIdx.x * 4 + wid;

    const float2 xv = ((const float2*)(x + (size_t)b * NDIM))[lane];
    const int yb = y[b];
    const int* __restrict__ idxb = idx + (size_t)b * KP1;
    const float2* __restrict__ mem2 = (const float2*)memory;
    float* __restrict__ outb = logits + (size_t)b * KP1;

    const int chunk = (KP1 + nwaves - 1) / nwaves;   // 129
    const int k0 = gwave * chunk;
    const int k1 = min(k0 + chunk, KP1);

    for (int k = k0; k < k1; k += U) {
        // 1) row indices (uniform-address broadcast loads, L1-resident walk)
        int j[U];
        #pragma unroll
        for (int u = 0; u < U; ++u) {
            int kc = k + u;
            kc = (kc < KP1) ? kc : (KP1 - 1);    // clamp tail (not stored)
            j[u] = (kc == 0) ? yb : idxb[kc];
        }
        // 2) 8 independent 512B coalesced gathers in flight
        float2 m[U];
        #pragma unroll
        for (int u = 0; u < U; ++u)
            m[u] = mem2[(size_t)j[u] * (NDIM / 2) + lane];
        // 3) partial dots
        float s[U];
        #pragma unroll
        for (int u = 0; u < U; ++u)
            s[u] = m[u].x * xv.x + m[u].y * xv.y;
        // 4) 8 interleaved butterflies: 6 steps, independent chains -> ILP
        #pragma unroll
        for (int o = 32; o > 0; o >>= 1) {
            #pragma unroll
            for (int u = 0; u < U; ++u)
                s[u] += __shfl_xor(s[u], o, 64);
        }
        // 5) lane u takes row k+u's sum; one coalesced masked 32B store
        float r = s[0];
        #pragma unroll
        for (int u = 1; u < U; ++u)
            r = (lane == u) ? s[u] : r;
        if (lane < U && (k + lane) < k1)
            outb[k + lane] = r * T_INV;
    }
}

// Streaming float4 copy: memory -> out_memory (256 MB each way).
__global__ __launch_bounds__(256) void copy_kernel(
        const float4* __restrict__ src,
        float4*       __restrict__ dst,
        int n4) {
    const int i = blockIdx.x * blockDim.x + threadIdx.x;
    if (i < n4) dst[i] = src[i];
}

// 16 blocks x 64 lanes: EMA-mix row y[b], normalize, scatter into out_mem.
// Runs AFTER copy_kernel (stream ordering) so it overwrites the stale copy.
__global__ __launch_bounds__(64) void update_kernel(
        const float* __restrict__ x,
        const int*   __restrict__ y,
        const float* __restrict__ memory,
        float*       __restrict__ labels,
        float*       __restrict__ out_mem) {
    const int b    = blockIdx.x;
    const int lane = threadIdx.x;
    const int yb   = y[b];
    const float2 m  = ((const float2*)(memory + (size_t)yb * NDIM))[lane];
    const float2 xv = ((const float2*)(x + (size_t)b * NDIM))[lane];
    float2 v;
    v.x = m.x * MOM + xv.x * (1.0f - MOM);
    v.y = m.y * MOM + xv.y * (1.0f - MOM);
    float s = v.x * v.x + v.y * v.y;
    #pragma unroll
    for (int off = 32; off > 0; off >>= 1)
        s += __shfl_xor(s, off, 64);          // butterfly: all lanes get sum
    const float n = fmaxf(sqrtf(s), EPS);
    float2 o; o.x = v.x / n; o.y = v.y / n;
    ((float2*)(out_mem + (size_t)yb * NDIM))[lane] = o;
    if (lane == 0) labels[b] = 0.0f;
}

extern "C" void kernel_launch(void* const* d_in, const int* in_sizes, int n_in,
                              void* d_out, int out_size, void* d_ws, size_t ws_size,
                              hipStream_t stream) {
    const float* x      = (const float*)d_in[0];
    const int*   y      = (const int*)  d_in[1];
    const int*   idx    = (const int*)  d_in[2];
    const float* memory = (const float*)d_in[3];

    float* logits  = (float*)d_out;                 // BSZ*KP1
    float* labels  = logits + (size_t)BSZ * KP1;    // BSZ
    float* out_mem = labels + BSZ;                  // NDATA*NDIM

    // 1) logits: persistent chunks, (NBX x BSZ) grid, 4 waves/block
    dim3 lgrid(NBX, BSZ);
    logits_kernel<<<lgrid, 256, 0, stream>>>(x, y, idx, memory, logits);

    // 2) full memory copy (float4)
    const int n4 = (int)(NDATA * NDIM / 4);
    copy_kernel<<<(n4 + 255) / 256, 256, 0, stream>>>(
        (const float4*)memory, (float4*)out_mem, n4);

    // 3) EMA update of the 16 positive rows + zero labels
    update_kernel<<<BSZ, 64, 0, stream>>>(x, y, memory, labels, out_mem);
}

// Round 3
// 156.359 us; speedup vs baseline: 1.8568x; 1.0959x over previous
//
#include <hip/hip_runtime.h>
#include <math.h>

// Problem constants (from reference setup_inputs)
constexpr int   BSZ   = 16;
constexpr int   NDIM  = 128;
constexpr int   KP1   = 65537;      // K+1
constexpr long  NDATA = 500000;
constexpr float T_INV = 1.0f / 0.07f;
constexpr float MOM   = 0.5f;
constexpr float EPS   = 1e-12f;

constexpr int U    = 8;    // rows in flight per wave iteration (MLP depth)
constexpr int NBX  = 128;  // logits blocks along k per batch row (2048 total)
constexpr int NCPY = 2048; // copy blocks
constexpr int N4   = (int)(NDATA * NDIM / 4);   // 16,000,000 float4

// Native clang vector type: __builtin_nontemporal_store requires a real
// vector type, not HIP's struct-based float4.
typedef float v4f __attribute__((ext_vector_type(4)));

// Merge two lane-parallel partial sums: halves the lane-span per value.
// For lanes with (lane&bit)==0 the result is a(l)+a(l^bit); for the others
// b(l)+b(l^bit). One cndmask + one shuffle + one add per merged pair.
__device__ __forceinline__ float merge_pair(float a, float b, int bit, int lane) {
    const float keep = (lane & bit) ? b : a;
    const float send = (lane & bit) ? a : b;
    return keep + __shfl_xor(send, bit, 64);
}

// Fused kernel: odd blocks compute logits (persistent row chunks), even
// blocks stream-copy memory -> out_mem (non-temporal stores so the 256MB
// write stream doesn't evict the 'memory' lines the gathers re-read from L3).
__global__ __launch_bounds__(256, 8) void fused_kernel(
        const float*  __restrict__ x,
        const int*    __restrict__ y,
        const int*    __restrict__ idx,
        const float*  __restrict__ memory,
        float*        __restrict__ logits,
        v4f*          __restrict__ out4) {
    const int bid = blockIdx.x;
    const int sub = bid >> 1;

    if ((bid & 1) == 0) {
        // ---- copy role: grid-stride float4 copy, NT stores ----
        const v4f* __restrict__ src = (const v4f*)memory;
        const int stride = NCPY * 256;
        for (int i = sub * 256 + threadIdx.x; i < N4; i += stride) {
            const v4f v = src[i];                    // regular load: warm L3
            __builtin_nontemporal_store(v, out4 + i);
        }
        return;
    }

    // ---- logits role ----
    const int bx   = sub & (NBX - 1);   // 0..127
    const int b    = sub >> 7;          // 0..15
    const int lane = threadIdx.x & 63;
    const int wid  = threadIdx.x >> 6;  // 0..3
    const int nwaves = NBX * 4;
    const int gwave  = bx * 4 + wid;

    const float2 xv = ((const float2*)(x + (size_t)b * NDIM))[lane];
    const int yb = y[b];
    const int* __restrict__ idxb = idx + (size_t)b * KP1;
    const float2* __restrict__ mem2 = (const float2*)memory;
    float* __restrict__ outb = logits + (size_t)b * KP1;

    const int chunk = (KP1 + nwaves - 1) / nwaves;   // 129
    const int k0 = gwave * chunk;
    const int k1 = min(k0 + chunk, KP1);

    for (int k = k0; k < k1; k += U) {
        // 1) row indices (wave-uniform broadcast loads)
        int j[U];
        #pragma unroll
        for (int u = 0; u < U; ++u) {
            int kc = k + u;
            kc = (kc < KP1) ? kc : (KP1 - 1);    // clamp tail (not stored)
            j[u] = (kc == 0) ? yb : idxb[kc];
        }
        // 2) 8 independent 512B coalesced gathers in flight
        float2 m[U];
        #pragma unroll
        for (int u = 0; u < U; ++u)
            m[u] = mem2[(size_t)j[u] * (NDIM / 2) + lane];
        // 3) partial dots
        float s[U];
        #pragma unroll
        for (int u = 0; u < U; ++u)
            s[u] = m[u].x * xv.x + m[u].y * xv.y;
        // 4) merge-tree reduction: 11 shuffles total (vs 48 butterfly).
        //    After the 3 merge levels, lane l holds value v=(l>>3)&7
        //    partially summed over flips of bits {8,16,32}.
        float m0 = merge_pair(s[0], s[4], 32, lane);
        float m1 = merge_pair(s[1], s[5], 32, lane);
        float m2 = merge_pair(s[2], s[6], 32, lane);
        float m3 = merge_pair(s[3], s[7], 32, lane);
        float n0 = merge_pair(m0, m2, 16, lane);
        float n1 = merge_pair(m1, m3, 16, lane);
        float p  = merge_pair(n0, n1, 8, lane);
        p += __shfl_xor(p, 4, 64);
        p += __shfl_xor(p, 2, 64);
        p += __shfl_xor(p, 1, 64);
        // value u fully reduced in every lane of group u (lanes 8u..8u+7)
        const float r = __shfl(p, (lane & 7) * 8, 64);
        if (lane < U && (k + lane) < k1)
            __builtin_nontemporal_store(r * T_INV, outb + k + lane);
    }
}

// 16 blocks x 64 lanes: EMA-mix row y[b], normalize, scatter into out_mem.
// Runs AFTER fused_kernel (stream ordering) so it overwrites the stale copy.
__global__ __launch_bounds__(64) void update_kernel(
        const float* __restrict__ x,
        const int*   __restrict__ y,
        const float* __restrict__ memory,
        float*       __restrict__ labels,
        float*       __restrict__ out_mem) {
    const int b    = blockIdx.x;
    const int lane = threadIdx.x;
    const int yb   = y[b];
    const float2 m  = ((const float2*)(memory + (size_t)yb * NDIM))[lane];
    const float2 xv = ((const float2*)(x + (size_t)b * NDIM))[lane];
    float2 v;
    v.x = m.x * MOM + xv.x * (1.0f - MOM);
    v.y = m.y * MOM + xv.y * (1.0f - MOM);
    float s = v.x * v.x + v.y * v.y;
    #pragma unroll
    for (int off = 32; off > 0; off >>= 1)
        s += __shfl_xor(s, off, 64);          // butterfly: all lanes get sum
    const float n = fmaxf(sqrtf(s), EPS);
    float2 o; o.x = v.x / n; o.y = v.y / n;
    ((float2*)(out_mem + (size_t)yb * NDIM))[lane] = o;
    if (lane == 0) labels[b] = 0.0f;
}

extern "C" void kernel_launch(void* const* d_in, const int* in_sizes, int n_in,
                              void* d_out, int out_size, void* d_ws, size_t ws_size,
                              hipStream_t stream) {
    const float* x      = (const float*)d_in[0];
    const int*   y      = (const int*)  d_in[1];
    const int*   idx    = (const int*)  d_in[2];
    const float* memory = (const float*)d_in[3];

    float* logits  = (float*)d_out;                 // BSZ*KP1
    float* labels  = logits + (size_t)BSZ * KP1;    // BSZ
    float* out_mem = labels + BSZ;                  // NDATA*NDIM

    // 1) fused logits + copy: even blocks copy, odd blocks logits
    const int nblocks = NCPY + NBX * BSZ;           // 2048 + 2048 = 4096
    fused_kernel<<<nblocks, 256, 0, stream>>>(
        x, y, idx, memory, logits, (v4f*)out_mem);

    // 2) EMA update of the 16 positive rows + zero labels
    update_kernel<<<BSZ, 64, 0, stream>>>(x, y, memory, labels, out_mem);
}

// Round 4
// 136.626 us; speedup vs baseline: 2.1250x; 1.1444x over previous
//
#include <hip/hip_runtime.h>
#include <math.h>

// Problem constants (from reference setup_inputs)
constexpr int   BSZ   = 16;
constexpr int   NDIM  = 128;
constexpr int   KP1   = 65537;      // K+1
constexpr long  NDATA = 500000;
constexpr float T_INV = 1.0f / 0.07f;
constexpr float MOM   = 0.5f;
constexpr float EPS   = 1e-12f;

typedef float v4f __attribute__((ext_vector_type(4)));

// ---------------- new path: sequential sweep + dots table ----------------
constexpr int  TROWS    = 64;                    // rows per tile (= lanes)
constexpr int  NTILES   = (int)((NDATA + TROWS - 1) / TROWS);   // 7813
constexpr int  LDP      = NDIM + 1;              // 129 pad: (r+d)%32 -> 2-way free
constexpr int  K1_BLOCKS = 1024;                 // 4 single-wave blocks/CU
constexpr int  NLOG     = BSZ * KP1;             // 1,048,592
constexpr int  K2_GBLK  = (NLOG + 255) / 256;    // 4097
constexpr long DOTS_ELEMS = (long)BSZ * NDATA;   // 8,000,000 floats (32 MB)
constexpr size_t WS_NEED = (size_t)(DOTS_ELEMS + BSZ * NDIM) * 4;

// k0: transpose x[16][128] -> xT[128][16] (workspace)
__global__ __launch_bounds__(256) void xpose_kernel(
        const float* __restrict__ x, float* __restrict__ xT) {
    const int t = blockIdx.x * 256 + threadIdx.x;
    if (t < BSZ * NDIM) {
        const int b = t >> 7, d = t & 127;
        xT[d * BSZ + b] = x[t];
    }
}

// k1: one sequential sweep over memory. Per 64-row tile (one wave):
//   NT-load -> NT-store to out (the copy) + ds_write to pad-129 LDS tile,
//   then lane l = row l: 128-step d-loop, 16 fp32 FMAs/step against
//   xT[dd][0..15] (wave-uniform -> scalar/L1 loads), dots stored coalesced.
// Single wave per block: no barriers; compiler orders LDS via lgkmcnt.
__global__ __launch_bounds__(64) void dots_copy_kernel(
        const float* __restrict__ memory,
        const float* __restrict__ xT,
        float*       __restrict__ dots,
        float*       __restrict__ out) {
    __shared__ float tile[TROWS * LDP];
    const int l = threadIdx.x;

    for (int t = blockIdx.x; t < NTILES; t += K1_BLOCKS) {
        const long j0   = (long)t * TROWS;
        const int  rows = (int)((NDATA - j0 < TROWS) ? (NDATA - j0) : TROWS);
        const v4f* __restrict__ src = (const v4f*)(memory + j0 * NDIM);
        v4f*       __restrict__ dst = (v4f*)(out + j0 * NDIM);

        if (rows == TROWS) {
            #pragma unroll 8
            for (int c = 0; c < TROWS * (NDIM / 4) / 64; ++c) {
                const int fi = c * 64 + l;
                const v4f v = __builtin_nontemporal_load(src + fi);
                __builtin_nontemporal_store(v, dst + fi);
                const int r = fi >> 5, col = (fi & 31) * 4;
                float* p = &tile[r * LDP + col];
                p[0] = v.x; p[1] = v.y; p[2] = v.z; p[3] = v.w;
            }
        } else {
            const int nf4 = rows * (NDIM / 4);
            for (int c = 0; c < TROWS * (NDIM / 4) / 64; ++c) {
                const int fi = c * 64 + l;
                if (fi < nf4) {
                    const v4f v = __builtin_nontemporal_load(src + fi);
                    __builtin_nontemporal_store(v, dst + fi);
                    const int r = fi >> 5, col = (fi & 31) * 4;
                    float* p = &tile[r * LDP + col];
                    p[0] = v.x; p[1] = v.y; p[2] = v.z; p[3] = v.w;
                }
            }
        }

        float acc[BSZ];
        #pragma unroll
        for (int b = 0; b < BSZ; ++b) acc[b] = 0.0f;

        const float* __restrict__ mrow = &tile[l * LDP];
        #pragma unroll 4
        for (int dd = 0; dd < NDIM; ++dd) {
            const float m = mrow[dd];               // 2-way bank alias: free
            const float* __restrict__ xv = &xT[dd * BSZ];   // wave-uniform
            #pragma unroll
            for (int b = 0; b < BSZ; ++b)
                acc[b] = fmaf(m, xv[b], acc[b]);
        }

        if (l < rows) {
            #pragma unroll
            for (int b = 0; b < BSZ; ++b)
                dots[(long)b * NDATA + j0 + l] = acc[b];   // 256B coalesced
        }
    }
}

// k2: logits gather from the L3-resident dots table + fused EMA update.
__global__ __launch_bounds__(256) void gather_kernel(
        const float* __restrict__ x,
        const int*   __restrict__ y,
        const int*   __restrict__ idx,
        const float* __restrict__ memory,
        const float* __restrict__ dots,
        float*       __restrict__ logits,
        float*       __restrict__ labels,
        float*       __restrict__ out_mem) {
    const int bid = blockIdx.x;
    if (bid < K2_GBLK) {
        const int g = bid * 256 + threadIdx.x;
        if (g < NLOG) {
            const int b = g / KP1;
            const int k = g - b * KP1;
            const int j = (k == 0) ? y[b] : idx[g];
            logits[g] = dots[(long)b * NDATA + j] * T_INV;
        }
        return;
    }
    // ---- update role: 16 blocks, one wave each ----
    const int b = bid - K2_GBLK;
    const int lane = threadIdx.x;
    if (lane >= 64) return;
    const int yb = y[b];
    const float2 m  = ((const float2*)(memory + (size_t)yb * NDIM))[lane];
    const float2 xv = ((const float2*)(x + (size_t)b * NDIM))[lane];
    float2 v;
    v.x = m.x * MOM + xv.x * (1.0f - MOM);
    v.y = m.y * MOM + xv.y * (1.0f - MOM);
    float s = v.x * v.x + v.y * v.y;
    #pragma unroll
    for (int off = 32; off > 0; off >>= 1)
        s += __shfl_xor(s, off, 64);
    const float n = fmaxf(sqrtf(s), EPS);
    float2 o; o.x = v.x / n; o.y = v.y / n;
    ((float2*)(out_mem + (size_t)yb * NDIM))[lane] = o;
    if (lane == 0) labels[b] = 0.0f;
}

// ---------------- fallback path (round-3 fused kernel) ----------------
constexpr int U    = 8;
constexpr int NBX  = 128;
constexpr int NCPY = 2048;
constexpr int N4   = (int)(NDATA * NDIM / 4);

__device__ __forceinline__ float merge_pair(float a, float b, int bit, int lane) {
    const float keep = (lane & bit) ? b : a;
    const float send = (lane & bit) ? a : b;
    return keep + __shfl_xor(send, bit, 64);
}

__global__ __launch_bounds__(256, 8) void fused_kernel(
        const float*  __restrict__ x,
        const int*    __restrict__ y,
        const int*    __restrict__ idx,
        const float*  __restrict__ memory,
        float*        __restrict__ logits,
        v4f*          __restrict__ out4) {
    const int bid = blockIdx.x;
    const int sub = bid >> 1;
    if ((bid & 1) == 0) {
        const v4f* __restrict__ src = (const v4f*)memory;
        const int stride = NCPY * 256;
        for (int i = sub * 256 + threadIdx.x; i < N4; i += stride) {
            const v4f v = src[i];
            __builtin_nontemporal_store(v, out4 + i);
        }
        return;
    }
    const int bx   = sub & (NBX - 1);
    const int b    = sub >> 7;
    const int lane = threadIdx.x & 63;
    const int wid  = threadIdx.x >> 6;
    const int nwaves = NBX * 4;
    const int gwave  = bx * 4 + wid;
    const float2 xv = ((const float2*)(x + (size_t)b * NDIM))[lane];
    const int yb = y[b];
    const int* __restrict__ idxb = idx + (size_t)b * KP1;
    const float2* __restrict__ mem2 = (const float2*)memory;
    float* __restrict__ outb = logits + (size_t)b * KP1;
    const int chunk = (KP1 + nwaves - 1) / nwaves;
    const int k0 = gwave * chunk;
    const int k1 = min(k0 + chunk, KP1);
    for (int k = k0; k < k1; k += U) {
        int j[U];
        #pragma unroll
        for (int u = 0; u < U; ++u) {
            int kc = k + u;
            kc = (kc < KP1) ? kc : (KP1 - 1);
            j[u] = (kc == 0) ? yb : idxb[kc];
        }
        float2 m[U];
        #pragma unroll
        for (int u = 0; u < U; ++u)
            m[u] = mem2[(size_t)j[u] * (NDIM / 2) + lane];
        float s[U];
        #pragma unroll
        for (int u = 0; u < U; ++u)
            s[u] = m[u].x * xv.x + m[u].y * xv.y;
        float m0 = merge_pair(s[0], s[4], 32, lane);
        float m1 = merge_pair(s[1], s[5], 32, lane);
        float m2 = merge_pair(s[2], s[6], 32, lane);
        float m3 = merge_pair(s[3], s[7], 32, lane);
        float n0 = merge_pair(m0, m2, 16, lane);
        float n1 = merge_pair(m1, m3, 16, lane);
        float p  = merge_pair(n0, n1, 8, lane);
        p += __shfl_xor(p, 4, 64);
        p += __shfl_xor(p, 2, 64);
        p += __shfl_xor(p, 1, 64);
        const float r = __shfl(p, (lane & 7) * 8, 64);
        if (lane < U && (k + lane) < k1)
            __builtin_nontemporal_store(r * T_INV, outb + k + lane);
    }
}

__global__ __launch_bounds__(64) void update_kernel(
        const float* __restrict__ x,
        const int*   __restrict__ y,
        const float* __restrict__ memory,
        float*       __restrict__ labels,
        float*       __restrict__ out_mem) {
    const int b    = blockIdx.x;
    const int lane = threadIdx.x;
    const int yb   = y[b];
    const float2 m  = ((const float2*)(memory + (size_t)yb * NDIM))[lane];
    const float2 xv = ((const float2*)(x + (size_t)b * NDIM))[lane];
    float2 v;
    v.x = m.x * MOM + xv.x * (1.0f - MOM);
    v.y = m.y * MOM + xv.y * (1.0f - MOM);
    float s = v.x * v.x + v.y * v.y;
    #pragma unroll
    for (int off = 32; off > 0; off >>= 1)
        s += __shfl_xor(s, off, 64);
    const float n = fmaxf(sqrtf(s), EPS);
    float2 o; o.x = v.x / n; o.y = v.y / n;
    ((float2*)(out_mem + (size_t)yb * NDIM))[lane] = o;
    if (lane == 0) labels[b] = 0.0f;
}

extern "C" void kernel_launch(void* const* d_in, const int* in_sizes, int n_in,
                              void* d_out, int out_size, void* d_ws, size_t ws_size,
                              hipStream_t stream) {
    const float* x      = (const float*)d_in[0];
    const int*   y      = (const int*)  d_in[1];
    const int*   idx    = (const int*)  d_in[2];
    const float* memory = (const float*)d_in[3];

    float* logits  = (float*)d_out;                 // BSZ*KP1
    float* labels  = logits + (size_t)BSZ * KP1;    // BSZ
    float* out_mem = labels + BSZ;                  // NDATA*NDIM

    if (d_ws != nullptr && ws_size >= WS_NEED) {
        float* dots = (float*)d_ws;                 // [16][500000] = 32 MB
        float* xT   = dots + DOTS_ELEMS;            // [128][16]

        xpose_kernel<<<(BSZ * NDIM + 255) / 256, 256, 0, stream>>>(x, xT);
        dots_copy_kernel<<<K1_BLOCKS, 64, 0, stream>>>(memory, xT, dots, out_mem);
        gather_kernel<<<K2_GBLK + BSZ, 256, 0, stream>>>(
            x, y, idx, memory, dots, logits, labels, out_mem);
    } else {
        const int nblocks = NCPY + NBX * BSZ;
        fused_kernel<<<nblocks, 256, 0, stream>>>(
            x, y, idx, memory, logits, (v4f*)out_mem);
        update_kernel<<<BSZ, 64, 0, stream>>>(x, y, memory, labels, out_mem);
    }
}